// Round 3
// baseline (411.237 us; speedup 1.0000x reference)
//
#include <hip/hip_runtime.h>

typedef __bf16 bf16x8 __attribute__((ext_vector_type(8)));
typedef float f32x4 __attribute__((ext_vector_type(4)));

#define D_MODEL 1024
#define NUM_HEADS 16
#define DK 64
#define BATCH 2
#define SEQ 2048
#define M_ROWS (BATCH*SEQ)

#define GLOAD_LDS16(gp, lp) __builtin_amdgcn_global_load_lds( \
    (__attribute__((address_space(1))) void*)(gp), \
    (__attribute__((address_space(3))) void*)(lp), 16, 0, 0)

// fp32 -> bf16 conversion, 8 elems/thread (16B bf16 store)
__global__ __launch_bounds__(256) void cvt_f32_bf16(
    const float* __restrict__ src, __bf16* __restrict__ dst, int n)
{
  int i = (blockIdx.x * 256 + threadIdx.x) * 8;
  if (i >= n) return;
  float4 a = *(const float4*)(src + i);
  float4 b = *(const float4*)(src + i + 4);
  bf16x8 o;
  o[0] = (__bf16)a.x; o[1] = (__bf16)a.y; o[2] = (__bf16)a.z; o[3] = (__bf16)a.w;
  o[4] = (__bf16)b.x; o[5] = (__bf16)b.y; o[6] = (__bf16)b.z; o[7] = (__bf16)b.w;
  *(bf16x8*)(dst + i) = o;
}

// C[M,N] = A[M,K] @ W[N,K]^T + bias[N]; A,W bf16, bias fp32, fp32 accum.
// OutT selects the store dtype (float for d_out, __bf16 for intermediates).
// m97-style: 128x128 tile, BK=32, 4 waves (2x2 of 64x64), global_load_lds w=16.
template <typename OutT>
__global__ __launch_bounds__(256) void gemm_bt_bias(
    const __bf16* __restrict__ A, const __bf16* __restrict__ W,
    const float* __restrict__ bias, OutT* __restrict__ C,
    int M, int N, int K)
{
  __shared__ __align__(16) __bf16 sA[128*32];
  __shared__ __align__(16) __bf16 sB[128*32];
  const int tid  = threadIdx.x;
  const int wave = tid >> 6;
  const int lane = tid & 63;
  const int l16  = lane & 15;
  const int quad = lane >> 4;
  const int m0 = blockIdx.y * 128;
  const int n0 = blockIdx.x * 128;
  const int wm = (wave >> 1) * 64;
  const int wn = (wave & 1) * 64;

  f32x4 acc[4][4] = {};

  // staging chunk c (16B = 8 bf16): row c/4, col (c%4)*8; lds byte off = c*16
  const int c0 = tid, c1 = tid + 256;
  const long aoff0 = (long)(m0 + (c0 >> 2)) * K + (c0 & 3) * 8;
  const long aoff1 = (long)(m0 + (c1 >> 2)) * K + (c1 & 3) * 8;
  const long boff0 = (long)(n0 + (c0 >> 2)) * K + (c0 & 3) * 8;
  const long boff1 = (long)(n0 + (c1 >> 2)) * K + (c1 & 3) * 8;

  for (int k0 = 0; k0 < K; k0 += 32) {
    __syncthreads();
    GLOAD_LDS16(A + aoff0 + k0, (char*)sA + wave * 1024);
    GLOAD_LDS16(A + aoff1 + k0, (char*)sA + 4096 + wave * 1024);
    GLOAD_LDS16(W + boff0 + k0, (char*)sB + wave * 1024);
    GLOAD_LDS16(W + boff1 + k0, (char*)sB + 4096 + wave * 1024);
    __syncthreads();
    bf16x8 af[4], bf[4];
#pragma unroll
    for (int i = 0; i < 4; i++)
      af[i] = *(const bf16x8*)&sA[(wm + i * 16 + l16) * 32 + quad * 8];
#pragma unroll
    for (int j = 0; j < 4; j++)
      bf[j] = *(const bf16x8*)&sB[(wn + j * 16 + l16) * 32 + quad * 8];
#pragma unroll
    for (int i = 0; i < 4; i++)
#pragma unroll
      for (int j = 0; j < 4; j++)
        acc[i][j] = __builtin_amdgcn_mfma_f32_16x16x32_bf16(af[i], bf[j], acc[i][j], 0, 0, 0);
  }

#pragma unroll
  for (int j = 0; j < 4; j++) {
    int col = n0 + wn + j * 16 + l16;
    float bv = bias[col];
#pragma unroll
    for (int i = 0; i < 4; i++) {
      long row0 = m0 + wm + i * 16 + quad * 4;
#pragma unroll
      for (int r = 0; r < 4; r++)
        C[(row0 + r) * N + col] = (OutT)(acc[i][j][r] + bv);
    }
  }
}

__device__ inline float red16_max(float v) {
  v = fmaxf(v, __shfl_xor(v, 1, 64));
  v = fmaxf(v, __shfl_xor(v, 2, 64));
  v = fmaxf(v, __shfl_xor(v, 4, 64));
  v = fmaxf(v, __shfl_xor(v, 8, 64));
  return v;
}
__device__ inline float red16_sum(float v) {
  v += __shfl_xor(v, 1, 64);
  v += __shfl_xor(v, 2, 64);
  v += __shfl_xor(v, 4, 64);
  v += __shfl_xor(v, 8, 64);
  return v;
}

// Flash attention: block = 64 q-rows of one (b,h). 4 waves x 16 q-rows.
// K-tiles of 128 keys. Q/K/V in [B*S][D_MODEL] bf16 layout.
__global__ __launch_bounds__(256) void attn_kernel(
    const __bf16* __restrict__ Q, const __bf16* __restrict__ K,
    const __bf16* __restrict__ V, __bf16* __restrict__ O)
{
  constexpr int SQ_LD = 72;   // 64 d + pad
  constexpr int SK_LD = 72;   // 64 d + pad
  constexpr int SV_LD = 136;  // 128 keys + pad
  constexpr int SP_LD = 136;  // 128 keys + pad

  __shared__ __align__(16) __bf16 sQ[64 * SQ_LD];
  __shared__ __align__(16) __bf16 sK[128 * SK_LD];
  __shared__ __align__(16) __bf16 sVt[DK * SV_LD];       // [d][key] transposed
  __shared__ __align__(16) __bf16 sP[4 * 16 * SP_LD];    // per-wave [16 q][128 key]

  const int tid  = threadIdx.x;
  const int wave = tid >> 6;
  const int lane = tid & 63;
  const int l16  = lane & 15;
  const int quad = lane >> 4;

  const int bh = blockIdx.y;
  const int b  = bh / NUM_HEADS, h = bh % NUM_HEADS;
  const int q0 = blockIdx.x * 64;
  const long base = (long)b * SEQ * D_MODEL + h * DK;  // elem offset of (b, s=0, h, d=0)

  // load Q tile [64 q][64 d]
  for (int c = tid; c < 64 * 8; c += 256) {
    int row = c >> 3, d0 = (c & 7) * 8;
    uint4 val = *(const uint4*)(Q + base + (long)(q0 + row) * D_MODEL + d0);
    *(uint4*)&sQ[row * SQ_LD + d0] = val;
  }

  float mprev[4], lsum[4];
  f32x4 o[4] = {};  // o[dt] reg r -> out[q=quad*4+r][d=dt*16+l16]
#pragma unroll
  for (int r = 0; r < 4; r++) { mprev[r] = -1e30f; lsum[r] = 0.f; }

  for (int kt0 = 0; kt0 < SEQ; kt0 += 128) {
    __syncthreads();
    // stage K tile [128 key][64 d]
    for (int c = tid; c < 128 * 8; c += 256) {
      int key = c >> 3, d0 = (c & 7) * 8;
      uint4 val = *(const uint4*)(K + base + (long)(kt0 + key) * D_MODEL + d0);
      *(uint4*)&sK[key * SK_LD + d0] = val;
    }
    // stage V transposed -> sVt[d][key]
    for (int c = tid; c < 128 * 8; c += 256) {
      int key = c >> 3, d0 = (c & 7) * 8;
      union { uint4 u; ushort s[8]; } val;
      val.u = *(const uint4*)(V + base + (long)(kt0 + key) * D_MODEL + d0);
#pragma unroll
      for (int j = 0; j < 8; j++)
        ((ushort*)sVt)[(d0 + j) * SV_LD + key] = val.s[j];
    }
    __syncthreads();

    // S = Q K^T / 8 : wave computes its 16 q-rows x 128 keys
    f32x4 sc[8];
    bf16x8 aq0 = *(const bf16x8*)&sQ[(wave * 16 + l16) * SQ_LD + quad * 8];
    bf16x8 aq1 = *(const bf16x8*)&sQ[(wave * 16 + l16) * SQ_LD + 32 + quad * 8];
#pragma unroll
    for (int nt = 0; nt < 8; nt++) {
      bf16x8 b0 = *(const bf16x8*)&sK[(nt * 16 + l16) * SK_LD + quad * 8];
      bf16x8 b1 = *(const bf16x8*)&sK[(nt * 16 + l16) * SK_LD + 32 + quad * 8];
      f32x4 z = {};
      z = __builtin_amdgcn_mfma_f32_16x16x32_bf16(aq0, b0, z, 0, 0, 0);
      z = __builtin_amdgcn_mfma_f32_16x16x32_bf16(aq1, b1, z, 0, 0, 0);
      sc[nt] = z * 0.125f;
    }

    // online softmax per q-row (row = quad*4 + r, key dim spread over 16 lanes)
    float alpha[4];
#pragma unroll
    for (int r = 0; r < 4; r++) {
      float mx = sc[0][r];
#pragma unroll
      for (int nt = 1; nt < 8; nt++) mx = fmaxf(mx, sc[nt][r]);
      mx = red16_max(mx);
      float mnew = fmaxf(mprev[r], mx);
      alpha[r] = __expf(mprev[r] - mnew);
      mprev[r] = mnew;
      float s = 0.f;
#pragma unroll
      for (int nt = 0; nt < 8; nt++) {
        float p = __expf(sc[nt][r] - mnew);
        sc[nt][r] = p;
        s += p;
      }
      s = red16_sum(s);
      lsum[r] = lsum[r] * alpha[r] + s;
    }
#pragma unroll
    for (int dt = 0; dt < 4; dt++)
#pragma unroll
      for (int r = 0; r < 4; r++) o[dt][r] *= alpha[r];

    // write P (bf16) to wave-private LDS in [q][key] layout
#pragma unroll
    for (int nt = 0; nt < 8; nt++)
#pragma unroll
      for (int r = 0; r < 4; r++)
        sP[(wave * 16 + quad * 4 + r) * SP_LD + nt * 16 + l16] = (__bf16)sc[nt][r];
    __syncthreads();

    // O += P @ V : A = P[q][key], B = V[key][d] read from sVt[d][key]
#pragma unroll
    for (int kt = 0; kt < 4; kt++) {
      bf16x8 ap = *(const bf16x8*)&sP[(wave * 16 + l16) * SP_LD + kt * 32 + quad * 8];
#pragma unroll
      for (int dt = 0; dt < 4; dt++) {
        bf16x8 bv = *(const bf16x8*)&sVt[(dt * 16 + l16) * SV_LD + kt * 32 + quad * 8];
        o[dt] = __builtin_amdgcn_mfma_f32_16x16x32_bf16(ap, bv, o[dt], 0, 0, 0);
      }
    }
  }

  // normalize and store to O in [B*S][D_MODEL] layout
#pragma unroll
  for (int dt = 0; dt < 4; dt++) {
#pragma unroll
    for (int r = 0; r < 4; r++) {
      int s = q0 + wave * 16 + quad * 4 + r;
      int d = dt * 16 + l16;
      O[base + (long)s * D_MODEL + d] = (__bf16)(o[dt][r] / lsum[r]);
    }
  }
}

extern "C" void kernel_launch(void* const* d_in, const int* in_sizes, int n_in,
                              void* d_out, int out_size, void* d_ws, size_t ws_size,
                              hipStream_t stream) {
  const float* q  = (const float*)d_in[0];
  const float* k  = (const float*)d_in[1];
  const float* v  = (const float*)d_in[2];
  const float* Wq = (const float*)d_in[3];
  const float* bq = (const float*)d_in[4];
  const float* Wk = (const float*)d_in[5];
  const float* bk = (const float*)d_in[6];
  const float* Wv = (const float*)d_in[7];
  const float* bv = (const float*)d_in[8];
  const float* Wo = (const float*)d_in[9];
  const float* bo = (const float*)d_in[10];
  float* out = (float*)d_out;   // fp32 output per reference output dtype

  const size_t ACT = (size_t)M_ROWS * D_MODEL;       // 4M elems
  const size_t WSZ = (size_t)D_MODEL * D_MODEL;      // 1M elems
  __bf16* qc  = (__bf16*)d_ws;          // converted inputs
  __bf16* kc  = qc + ACT;
  __bf16* vc  = kc + ACT;
  __bf16* Wqc = vc + ACT;               // converted weights
  __bf16* Wkc = Wqc + WSZ;
  __bf16* Wvc = Wkc + WSZ;
  __bf16* Woc = Wvc + WSZ;
  __bf16* wsQ = Woc + WSZ;              // projections
  __bf16* wsK = wsQ + ACT;
  __bf16* wsV = wsK + ACT;
  __bf16* wsAo = qc;                    // attn out reuses qc (qc dead after gemm #1)

  dim3 blk(256);
  // conversions
  cvt_f32_bf16<<<dim3(ACT / (256 * 8)), blk, 0, stream>>>(q, qc, (int)ACT);
  cvt_f32_bf16<<<dim3(ACT / (256 * 8)), blk, 0, stream>>>(k, kc, (int)ACT);
  cvt_f32_bf16<<<dim3(ACT / (256 * 8)), blk, 0, stream>>>(v, vc, (int)ACT);
  cvt_f32_bf16<<<dim3(WSZ / (256 * 8)), blk, 0, stream>>>(Wq, Wqc, (int)WSZ);
  cvt_f32_bf16<<<dim3(WSZ / (256 * 8)), blk, 0, stream>>>(Wk, Wkc, (int)WSZ);
  cvt_f32_bf16<<<dim3(WSZ / (256 * 8)), blk, 0, stream>>>(Wv, Wvc, (int)WSZ);
  cvt_f32_bf16<<<dim3(WSZ / (256 * 8)), blk, 0, stream>>>(Wo, Woc, (int)WSZ);

  dim3 g1(D_MODEL / 128, M_ROWS / 128);
  gemm_bt_bias<__bf16><<<g1, blk, 0, stream>>>(qc, Wqc, bq, wsQ, M_ROWS, D_MODEL, D_MODEL);
  gemm_bt_bias<__bf16><<<g1, blk, 0, stream>>>(kc, Wkc, bk, wsK, M_ROWS, D_MODEL, D_MODEL);
  gemm_bt_bias<__bf16><<<g1, blk, 0, stream>>>(vc, Wvc, bv, wsV, M_ROWS, D_MODEL, D_MODEL);
  dim3 g2(SEQ / 64, BATCH * NUM_HEADS);
  attn_kernel<<<g2, blk, 0, stream>>>(wsQ, wsK, wsV, wsAo);
  gemm_bt_bias<float><<<g1, blk, 0, stream>>>(wsAo, Woc, bo, out, M_ROWS, D_MODEL, D_MODEL);
}

// Round 4
// 335.929 us; speedup vs baseline: 1.2242x; 1.2242x over previous
//
#include <hip/hip_runtime.h>

typedef __bf16 bf16x8 __attribute__((ext_vector_type(8)));
typedef float f32x4 __attribute__((ext_vector_type(4)));

#define D_MODEL 1024
#define NUM_HEADS 16
#define DK 64
#define BATCH 2
#define SEQ 2048
#define M_ROWS (BATCH*SEQ)

#define GLOAD_LDS16(gp, lp) __builtin_amdgcn_global_load_lds( \
    (__attribute__((address_space(1))) void*)(gp), \
    (__attribute__((address_space(3))) void*)(lp), 16, 0, 0)

// fp32 -> bf16, 8 elems/thread; 3 tensors via blockIdx.y (dsts contiguous)
__global__ __launch_bounds__(256) void cvt3(
    const float* __restrict__ s0, const float* __restrict__ s1,
    const float* __restrict__ s2, __bf16* __restrict__ dst, int n)
{
  const float* s = blockIdx.y == 0 ? s0 : (blockIdx.y == 1 ? s1 : s2);
  __bf16* d = dst + (size_t)blockIdx.y * n;
  int i = (blockIdx.x * 256 + threadIdx.x) * 8;
  if (i >= n) return;
  float4 a = *(const float4*)(s + i);
  float4 b = *(const float4*)(s + i + 4);
  bf16x8 o;
  o[0] = (__bf16)a.x; o[1] = (__bf16)a.y; o[2] = (__bf16)a.z; o[3] = (__bf16)a.w;
  o[4] = (__bf16)b.x; o[5] = (__bf16)b.y; o[6] = (__bf16)b.z; o[7] = (__bf16)b.w;
  *(bf16x8*)(d + i) = o;
}

__global__ __launch_bounds__(256) void cvt4(
    const float* __restrict__ s0, const float* __restrict__ s1,
    const float* __restrict__ s2, const float* __restrict__ s3,
    __bf16* __restrict__ dst, int n)
{
  const float* s = blockIdx.y == 0 ? s0 : (blockIdx.y == 1 ? s1 :
                   (blockIdx.y == 2 ? s2 : s3));
  __bf16* d = dst + (size_t)blockIdx.y * n;
  int i = (blockIdx.x * 256 + threadIdx.x) * 8;
  if (i >= n) return;
  float4 a = *(const float4*)(s + i);
  float4 b = *(const float4*)(s + i + 4);
  bf16x8 o;
  o[0] = (__bf16)a.x; o[1] = (__bf16)a.y; o[2] = (__bf16)a.z; o[3] = (__bf16)a.w;
  o[4] = (__bf16)b.x; o[5] = (__bf16)b.y; o[6] = (__bf16)b.z; o[7] = (__bf16)b.w;
  *(bf16x8*)(d + i) = o;
}

// Core 128x128 GEMM tile body: C = A @ W^T + bias. OutT = store dtype.
template <typename OutT>
__device__ __forceinline__ void gemm_body(
    const __bf16* __restrict__ A, const __bf16* __restrict__ W,
    const float* __restrict__ bias, OutT* __restrict__ C,
    int M, int N, int K, int m0, int n0)
{
  __shared__ __align__(16) __bf16 sA[128*32];
  __shared__ __align__(16) __bf16 sB[128*32];
  const int tid  = threadIdx.x;
  const int wave = tid >> 6;
  const int lane = tid & 63;
  const int l16  = lane & 15;
  const int quad = lane >> 4;
  const int wm = (wave >> 1) * 64;
  const int wn = (wave & 1) * 64;

  f32x4 acc[4][4] = {};

  const int c0 = tid, c1 = tid + 256;
  const long aoff0 = (long)(m0 + (c0 >> 2)) * K + (c0 & 3) * 8;
  const long aoff1 = (long)(m0 + (c1 >> 2)) * K + (c1 & 3) * 8;
  const long boff0 = (long)(n0 + (c0 >> 2)) * K + (c0 & 3) * 8;
  const long boff1 = (long)(n0 + (c1 >> 2)) * K + (c1 & 3) * 8;

  for (int k0 = 0; k0 < K; k0 += 32) {
    __syncthreads();
    GLOAD_LDS16(A + aoff0 + k0, (char*)sA + wave * 1024);
    GLOAD_LDS16(A + aoff1 + k0, (char*)sA + 4096 + wave * 1024);
    GLOAD_LDS16(W + boff0 + k0, (char*)sB + wave * 1024);
    GLOAD_LDS16(W + boff1 + k0, (char*)sB + 4096 + wave * 1024);
    __syncthreads();
    bf16x8 af[4], bf[4];
#pragma unroll
    for (int i = 0; i < 4; i++)
      af[i] = *(const bf16x8*)&sA[(wm + i * 16 + l16) * 32 + quad * 8];
#pragma unroll
    for (int j = 0; j < 4; j++)
      bf[j] = *(const bf16x8*)&sB[(wn + j * 16 + l16) * 32 + quad * 8];
#pragma unroll
    for (int i = 0; i < 4; i++)
#pragma unroll
      for (int j = 0; j < 4; j++)
        acc[i][j] = __builtin_amdgcn_mfma_f32_16x16x32_bf16(af[i], bf[j], acc[i][j], 0, 0, 0);
  }

#pragma unroll
  for (int j = 0; j < 4; j++) {
    int col = n0 + wn + j * 16 + l16;
    float bv = bias[col];
#pragma unroll
    for (int i = 0; i < 4; i++) {
      long row0 = m0 + wm + i * 16 + quad * 4;
#pragma unroll
      for (int r = 0; r < 4; r++)
        C[(row0 + r) * N + col] = (OutT)(acc[i][j][r] + bv);
    }
  }
}

// Batched QKV projection: z in {0,1,2} selects slice of contiguous A/W/C, bias ptr.
__global__ __launch_bounds__(256) void gemm_qkv(
    const __bf16* __restrict__ Abase, const __bf16* __restrict__ Wbase,
    const float* __restrict__ b0, const float* __restrict__ b1,
    const float* __restrict__ b2, __bf16* __restrict__ Cbase)
{
  int z = blockIdx.z;
  const __bf16* A = Abase + (size_t)z * M_ROWS * D_MODEL;
  const __bf16* W = Wbase + (size_t)z * D_MODEL * D_MODEL;
  const float* bias = z == 0 ? b0 : (z == 1 ? b1 : b2);
  __bf16* C = Cbase + (size_t)z * M_ROWS * D_MODEL;
  gemm_body<__bf16>(A, W, bias, C, M_ROWS, D_MODEL, D_MODEL,
                    blockIdx.y * 128, blockIdx.x * 128);
}

__global__ __launch_bounds__(256) void gemm_out(
    const __bf16* __restrict__ A, const __bf16* __restrict__ W,
    const float* __restrict__ bias, float* __restrict__ C)
{
  gemm_body<float>(A, W, bias, C, M_ROWS, D_MODEL, D_MODEL,
                   blockIdx.y * 128, blockIdx.x * 128);
}

__device__ inline float red16_max(float v) {
  v = fmaxf(v, __shfl_xor(v, 1, 64));
  v = fmaxf(v, __shfl_xor(v, 2, 64));
  v = fmaxf(v, __shfl_xor(v, 4, 64));
  v = fmaxf(v, __shfl_xor(v, 8, 64));
  return v;
}
__device__ inline float red16_sum(float v) {
  v += __shfl_xor(v, 1, 64);
  v += __shfl_xor(v, 2, 64);
  v += __shfl_xor(v, 4, 64);
  v += __shfl_xor(v, 8, 64);
  return v;
}

// Flash attention: block = 64 q-rows of one (b,h). 4 waves x 16 q-rows.
// K-tiles of 128 keys. Q fragments register-resident (no sQ LDS).
__global__ __launch_bounds__(256) void attn_kernel(
    const __bf16* __restrict__ Q, const __bf16* __restrict__ K,
    const __bf16* __restrict__ V, __bf16* __restrict__ O)
{
  constexpr int SK_LD = 72;   // 64 d + pad
  constexpr int SV_LD = 136;  // 128 keys + pad (mult of 8: 16B-aligned b128 reads)
  constexpr int SP_LD = 136;

  __shared__ __align__(16) __bf16 sK[128 * SK_LD];
  __shared__ __align__(16) __bf16 sVt[DK * SV_LD];    // [d][key] transposed
  __shared__ __align__(16) __bf16 sP[64 * SP_LD];     // per-wave [16 q][128 key]

  const int tid  = threadIdx.x;
  const int wave = tid >> 6;
  const int lane = tid & 63;
  const int l16  = lane & 15;
  const int quad = lane >> 4;

  const int bh = blockIdx.y;
  const int b  = bh >> 4, h = bh & (NUM_HEADS - 1);
  const int q0 = blockIdx.x * 64;
  const long base = (long)b * SEQ * D_MODEL + h * DK;

  // Q A-fragments direct from global into registers (held for whole kernel)
  const __bf16* qrow = Q + base + (long)(q0 + wave * 16 + l16) * D_MODEL + quad * 8;
  const bf16x8 aq0 = *(const bf16x8*)(qrow);
  const bf16x8 aq1 = *(const bf16x8*)(qrow + 32);

  float mprev[4], lsum[4];
  f32x4 o[4] = {};  // o[dt] reg r -> out[q=quad*4+r][d=dt*16+l16]
#pragma unroll
  for (int r = 0; r < 4; r++) { mprev[r] = -1e30f; lsum[r] = 0.f; }

  // sVt staging indices: thread owns key-pair kp (0..63) at d-groups wave*8, wave*8+32
  const int kp = lane;           // within wave: 64 key-pairs
  const int vd0 = wave * 8;      // +32 on second iteration

  for (int kt0 = 0; kt0 < SEQ; kt0 += 128) {
    __syncthreads();
    // stage K tile [128 key][64 d], vectorized
    for (int c = tid; c < 128 * 8; c += 256) {
      int key = c >> 3, d0 = (c & 7) * 8;
      uint4 val = *(const uint4*)(K + base + (long)(kt0 + key) * D_MODEL + d0);
      *(uint4*)&sK[key * SK_LD + d0] = val;
    }
    // stage V transposed, pair-packed b32 writes: bank = (4*d + kp) % 32,
    // kp spans 0..63 per wave -> 2-way (free)
#pragma unroll
    for (int it = 0; it < 2; it++) {
      int d0 = vd0 + it * 32;
      const __bf16* vp = V + base + (long)(kt0 + 2 * kp) * D_MODEL + d0;
      uint4 v0 = *(const uint4*)(vp);
      uint4 v1 = *(const uint4*)(vp + D_MODEL);
      const ushort* e0 = (const ushort*)&v0;
      const ushort* e1 = (const ushort*)&v1;
      uint* dst = (uint*)sVt;
#pragma unroll
      for (int j = 0; j < 8; j++)
        dst[(d0 + j) * (SV_LD / 2) + kp] = (uint)e0[j] | ((uint)e1[j] << 16);
    }
    __syncthreads();

    // S = Q K^T / 8 : wave computes its 16 q-rows x 128 keys
    f32x4 sc[8];
#pragma unroll
    for (int nt = 0; nt < 8; nt++) {
      bf16x8 b0 = *(const bf16x8*)&sK[(nt * 16 + l16) * SK_LD + quad * 8];
      bf16x8 b1 = *(const bf16x8*)&sK[(nt * 16 + l16) * SK_LD + 32 + quad * 8];
      f32x4 z = {};
      z = __builtin_amdgcn_mfma_f32_16x16x32_bf16(aq0, b0, z, 0, 0, 0);
      z = __builtin_amdgcn_mfma_f32_16x16x32_bf16(aq1, b1, z, 0, 0, 0);
      sc[nt] = z * 0.125f;
    }

    // online softmax per q-row (row = quad*4 + r, key dim spread over 16 lanes)
    float alpha[4];
#pragma unroll
    for (int r = 0; r < 4; r++) {
      float mx = sc[0][r];
#pragma unroll
      for (int nt = 1; nt < 8; nt++) mx = fmaxf(mx, sc[nt][r]);
      mx = red16_max(mx);
      float mnew = fmaxf(mprev[r], mx);
      alpha[r] = __expf(mprev[r] - mnew);
      mprev[r] = mnew;
      float s = 0.f;
#pragma unroll
      for (int nt = 0; nt < 8; nt++) {
        float p = __expf(sc[nt][r] - mnew);
        sc[nt][r] = p;
        s += p;
      }
      s = red16_sum(s);
      lsum[r] = lsum[r] * alpha[r] + s;
    }
#pragma unroll
    for (int dt = 0; dt < 4; dt++)
#pragma unroll
      for (int r = 0; r < 4; r++) o[dt][r] *= alpha[r];

    // write P (bf16) to wave-private LDS [16 q][128 key]; no barrier needed
#pragma unroll
    for (int nt = 0; nt < 8; nt++)
#pragma unroll
      for (int r = 0; r < 4; r++)
        sP[(wave * 16 + quad * 4 + r) * SP_LD + nt * 16 + l16] = (__bf16)sc[nt][r];

    // O += P @ V : A = P[q][key], B from sVt[d][key]
#pragma unroll
    for (int kt = 0; kt < 4; kt++) {
      bf16x8 ap = *(const bf16x8*)&sP[(wave * 16 + l16) * SP_LD + kt * 32 + quad * 8];
#pragma unroll
      for (int dt = 0; dt < 4; dt++) {
        bf16x8 bv = *(const bf16x8*)&sVt[(dt * 16 + l16) * SV_LD + kt * 32 + quad * 8];
        o[dt] = __builtin_amdgcn_mfma_f32_16x16x32_bf16(ap, bv, o[dt], 0, 0, 0);
      }
    }
  }

  // normalize and store
#pragma unroll
  for (int dt = 0; dt < 4; dt++) {
#pragma unroll
    for (int r = 0; r < 4; r++) {
      int s = q0 + wave * 16 + quad * 4 + r;
      int d = dt * 16 + l16;
      O[base + (long)s * D_MODEL + d] = (__bf16)(o[dt][r] / lsum[r]);
    }
  }
}

extern "C" void kernel_launch(void* const* d_in, const int* in_sizes, int n_in,
                              void* d_out, int out_size, void* d_ws, size_t ws_size,
                              hipStream_t stream) {
  const float* q  = (const float*)d_in[0];
  const float* k  = (const float*)d_in[1];
  const float* v  = (const float*)d_in[2];
  const float* Wq = (const float*)d_in[3];
  const float* bq = (const float*)d_in[4];
  const float* Wk = (const float*)d_in[5];
  const float* bk = (const float*)d_in[6];
  const float* Wv = (const float*)d_in[7];
  const float* bv = (const float*)d_in[8];
  const float* Wo = (const float*)d_in[9];
  const float* bo = (const float*)d_in[10];
  float* out = (float*)d_out;

  const size_t ACT = (size_t)M_ROWS * D_MODEL;       // 4M elems
  const size_t WSZ = (size_t)D_MODEL * D_MODEL;      // 1M elems
  __bf16* qc  = (__bf16*)d_ws;          // qc,kc,vc contiguous
  __bf16* Wqc = qc + 3 * ACT;           // Wq,Wk,Wv,Wo contiguous
  __bf16* wsQ = Wqc + 4 * WSZ;          // Q,K,V projections contiguous
  __bf16* wsAo = qc;                    // attn out reuses qc (dead after QKV gemm)

  dim3 blk(256);
  cvt3<<<dim3(ACT / 2048, 3), blk, 0, stream>>>(q, k, v, qc, (int)ACT);
  cvt4<<<dim3(WSZ / 2048, 4), blk, 0, stream>>>(Wq, Wk, Wv, Wo, Wqc, (int)WSZ);

  gemm_qkv<<<dim3(D_MODEL / 128, M_ROWS / 128, 3), blk, 0, stream>>>(
      qc, Wqc, bq, bk, bv, wsQ);

  attn_kernel<<<dim3(SEQ / 64, BATCH * NUM_HEADS), blk, 0, stream>>>(
      wsQ, wsQ + ACT, wsQ + 2 * ACT, wsAo);

  gemm_out<<<dim3(D_MODEL / 128, M_ROWS / 128), blk, 0, stream>>>(
      wsAo, Wqc + 3 * WSZ, bo, out);
}